// Round 1
// baseline (1013.485 us; speedup 1.0000x reference)
//
#include <hip/hip_runtime.h>
#include <hip/hip_bf16.h>

#define NN 50000
#define NE 400000
#define AVG_LOG_F 2.1972245773362196f
#define EPSV 1e-5f

typedef __hip_bfloat16 bf16;

__device__ __forceinline__ float b2f(bf16 v){ return __bfloat162float(v); }
__device__ __forceinline__ bf16  f2b(float v){ return __float2bfloat16(v); }

// ---------- h0[n][d] = sum_c atom_emb[c][x[n][c]][d] ----------
__global__ void k_h0(const int* __restrict__ x, const float* __restrict__ aemb,
                     float* __restrict__ h0){
  int idx = blockIdx.x * 256 + threadIdx.x;
  if (idx >= NN * 64) return;
  int n = idx >> 6, d = idx & 63;
  float acc = 0.f;
  #pragma unroll
  for (int c = 0; c < 9; ++c){
    int a = x[n * 9 + c];
    acc += aemb[(c * 64 + a) * 64 + d];
  }
  h0[idx] = acc;
}

// ---------- degree histogram + bond code ----------
__global__ void k_deg_code(const int* __restrict__ ei, const int* __restrict__ ea,
                           int* __restrict__ deg, int* __restrict__ code){
  int e = blockIdx.x * 256 + threadIdx.x;
  if (e >= NE) return;
  int dst = ei[NE + e];
  atomicAdd(&deg[dst], 1);
  code[e] = ea[e * 3] + 8 * ea[e * 3 + 1] + 64 * ea[e * 3 + 2];
}

// ---------- exclusive scan of deg -> rowptr (3 kernels) ----------
__global__ void k_scan1(const int* __restrict__ deg, int* __restrict__ rowptr,
                        int* __restrict__ part){
  __shared__ int s[256];
  int t = threadIdx.x, i = blockIdx.x * 256 + t;
  int v = (i < NN) ? deg[i] : 0;
  s[t] = v; __syncthreads();
  for (int off = 1; off < 256; off <<= 1){
    int xv = (t >= off) ? s[t - off] : 0;
    __syncthreads();
    s[t] += xv;
    __syncthreads();
  }
  if (i < NN) rowptr[i] = s[t] - v;
  if (t == 255) part[blockIdx.x] = s[255];
}

__global__ void k_scan2(int* __restrict__ part, int nblk){
  __shared__ int s[256];
  int t = threadIdx.x;
  int v = (t < nblk) ? part[t] : 0;
  s[t] = v; __syncthreads();
  for (int off = 1; off < 256; off <<= 1){
    int xv = (t >= off) ? s[t - off] : 0;
    __syncthreads();
    s[t] += xv;
    __syncthreads();
  }
  if (t < nblk) part[t] = s[t] - v;   // exclusive block offsets
}

__global__ void k_scan3(int* __restrict__ rowptr, const int* __restrict__ part,
                        const int* __restrict__ deg, float* __restrict__ amp,
                        float* __restrict__ att){
  int i = blockIdx.x * 256 + threadIdx.x;
  if (i < NN){
    rowptr[i] += part[blockIdx.x];
    int d = deg[i];
    float ld = logf((float)max(d, 1) + 1.0f);
    amp[i] = ld / AVG_LOG_F;
    att[i] = AVG_LOG_F / ld;
  }
  if (i == 0) rowptr[NN] = NE;
}

// ---------- scatter edges into CSR order ----------
__global__ void k_scatter(const int* __restrict__ ei, const int* __restrict__ code,
                          const int* __restrict__ rowptr, int* __restrict__ cursor,
                          int* __restrict__ ssrc, int* __restrict__ scode){
  int e = blockIdx.x * 256 + threadIdx.x;
  if (e >= NE) return;
  int dst = ei[NE + e];
  int pos = rowptr[dst] + atomicAdd(&cursor[dst], 1);
  ssrc[pos]  = ei[e];
  scode[pos] = code[e];
}

// ---------- C table: ctab[code][l][d] = (sum_c bond_emb[c][attr_c]) @ preW_e[l] ----------
__global__ void k_ctab(const float* __restrict__ bemb, const float* __restrict__ preW,
                       bf16* __restrict__ ctab){
  __shared__ float et[64];
  int cb = blockIdx.x, l = blockIdx.y, t = threadIdx.x;
  int a0 = cb & 7, a1 = (cb >> 3) & 7, a2 = (cb >> 6) & 7;
  et[t] = bemb[(0 * 8 + a0) * 64 + t] + bemb[(1 * 8 + a1) * 64 + t] + bemb[(2 * 8 + a2) * 64 + t];
  __syncthreads();
  float acc = 0.f;
  const float* W = preW + (l * 192 + 128) * 64;
  for (int k = 0; k < 64; ++k) acc += et[k] * W[k * 64 + t];
  ctab[(cb * 5 + l) * 64 + t] = f2b(acc);
}

// ---------- Whsum = sum_l post_W[l][768:832], bsum = sum_l post_b[l] ----------
__global__ void k_whsum(const float* __restrict__ postW, const float* __restrict__ postb,
                        float* __restrict__ whs, float* __restrict__ bs){
  int idx = blockIdx.x * 256 + threadIdx.x;
  if (idx < 4096){
    int k = idx >> 6, d = idx & 63;
    float a = 0.f;
    for (int l = 0; l < 5; ++l) a += postW[(size_t)(l * 832 + 768 + k) * 64 + d];
    whs[idx] = a;
  }
  if (idx < 64){
    float a = 0.f;
    for (int l = 0; l < 5; ++l) a += postb[l * 64 + idx];
    bs[idx] = a;
  }
}

// ---------- AB GEMM: AB[n][s][64], s<5: A_l=h0@Wdst+b ; s>=5: B_l=h0@Wsrc ----------
__global__ __launch_bounds__(256) void k_ab(const float* __restrict__ h0,
                                            const float* __restrict__ preW,
                                            const float* __restrict__ preb,
                                            bf16* __restrict__ AB){
  __shared__ float As[64][65];  // [row][k]
  __shared__ float Ws[64][64];  // [k][col]
  const int s  = blockIdx.y;
  const int n0 = blockIdx.x * 64;
  const int t  = threadIdx.y * 16 + threadIdx.x;
  const int l  = (s < 5) ? s : (s - 5);
  const int rbase = l * 192 + ((s < 5) ? 0 : 64);
  #pragma unroll
  for (int i = 0; i < 16; ++i){
    int idx = t + i * 256;
    int r = idx >> 6, k = idx & 63;
    As[r][k] = (n0 + r < NN) ? h0[(size_t)(n0 + r) * 64 + k] : 0.f;
    Ws[r][k] = preW[(size_t)(rbase + r) * 64 + k];
  }
  __syncthreads();
  const int tx = threadIdx.x, ty = threadIdx.y;
  float acc[4][4] = {};
  for (int k = 0; k < 64; ++k){
    float a[4];
    #pragma unroll
    for (int i = 0; i < 4; ++i) a[i] = As[ty * 4 + i][k];
    float4 bv = *(const float4*)&Ws[k][tx * 4];
    float b[4] = {bv.x, bv.y, bv.z, bv.w};
    #pragma unroll
    for (int i = 0; i < 4; ++i)
      #pragma unroll
      for (int j = 0; j < 4; ++j)
        acc[i][j] += a[i] * b[j];
  }
  #pragma unroll
  for (int i = 0; i < 4; ++i){
    int n = n0 + ty * 4 + i;
    if (n >= NN) continue;
    #pragma unroll
    for (int j = 0; j < 4; ++j){
      int c = tx * 4 + j;
      float v = acc[i][j] + ((s < 5) ? preb[l * 64 + c] : 0.f);
      AB[(size_t)n * 640 + s * 64 + c] = f2b(v);
    }
  }
}

// ---------- h_lin = h0 + h0@Whsum + bsum  (written to d_out as base) ----------
__global__ __launch_bounds__(256) void k_hlin(const float* __restrict__ h0,
                                              const float* __restrict__ whs,
                                              const float* __restrict__ bs,
                                              float* __restrict__ out){
  __shared__ float As[64][65];
  __shared__ float Ws[64][64];
  const int n0 = blockIdx.x * 64;
  const int t  = threadIdx.y * 16 + threadIdx.x;
  #pragma unroll
  for (int i = 0; i < 16; ++i){
    int idx = t + i * 256;
    int r = idx >> 6, k = idx & 63;
    As[r][k] = (n0 + r < NN) ? h0[(size_t)(n0 + r) * 64 + k] : 0.f;
    Ws[r][k] = whs[idx];
  }
  __syncthreads();
  const int tx = threadIdx.x, ty = threadIdx.y;
  float acc[4][4] = {};
  for (int k = 0; k < 64; ++k){
    float a[4];
    #pragma unroll
    for (int i = 0; i < 4; ++i) a[i] = As[ty * 4 + i][k];
    float4 bv = *(const float4*)&Ws[k][tx * 4];
    float b[4] = {bv.x, bv.y, bv.z, bv.w};
    #pragma unroll
    for (int i = 0; i < 4; ++i)
      #pragma unroll
      for (int j = 0; j < 4; ++j)
        acc[i][j] += a[i] * b[j];
  }
  #pragma unroll
  for (int i = 0; i < 4; ++i){
    int n = n0 + ty * 4 + i;
    if (n >= NN) continue;
    #pragma unroll
    for (int j = 0; j < 4; ++j){
      int c = tx * 4 + j;
      out[(size_t)n * 64 + c] = acc[i][j] + h0[(size_t)n * 64 + c] + bs[c];
    }
  }
}

// ---------- per-node aggregation for layer l -> agg[n][256] bf16 ----------
__global__ __launch_bounds__(256) void k_agg(const bf16* __restrict__ AB,
                                             const bf16* __restrict__ ctab,
                                             const int* __restrict__ rowptr,
                                             const int* __restrict__ ssrc,
                                             const int* __restrict__ scode,
                                             const int l, bf16* __restrict__ agg){
  int w = threadIdx.x >> 6, lane = threadIdx.x & 63;
  int n = blockIdx.x * 4 + w;
  if (n >= NN) return;
  int r0 = rowptr[n], r1 = rowptr[n + 1];
  float s = 0.f, sq = 0.f, mx = -1e30f, mn = 1e30f;
  for (int j = r0; j < r1; ++j){
    int src = ssrc[j], cd = scode[j];
    float tv = b2f(AB[(size_t)src * 640 + (5 + l) * 64 + lane]) +
               b2f(ctab[(cd * 5 + l) * 64 + lane]);
    s += tv; sq += tv * tv;
    mx = fmaxf(mx, tv); mn = fminf(mn, tv);
  }
  int d = r1 - r0;
  float degc = (float)((d > 0) ? d : 1);
  float K = b2f(AB[(size_t)n * 640 + l * 64 + lane]);   // includes pre_b
  float mean = ((float)d * K + s) / degc;
  float MX = (d > 0) ? (K + mx) : 0.f;
  float MN = (d > 0) ? (K + mn) : 0.f;
  float mu = s / degc;
  float var = fmaxf(sq / degc - mu * mu, 0.f);
  float sd = sqrtf(var + EPSV);
  size_t base = (size_t)n * 256 + lane;
  agg[base]       = f2b(mean);
  agg[base + 64]  = f2b(MX);
  agg[base + 128] = f2b(MN);
  agg[base + 192] = f2b(sd);
}

// ---------- posttrans for layer l: out += U + amp*V + att*W ----------
__global__ __launch_bounds__(256) void k_post(const bf16* __restrict__ agg,
                                              const float* __restrict__ postW,
                                              const int l,
                                              const float* __restrict__ amp,
                                              const float* __restrict__ att,
                                              float* __restrict__ out){
  __shared__ float As[64][33];  // [row][k], k tile of 32
  __shared__ float Ws[32][64];  // [k][col]
  const int n0 = blockIdx.x * 64;
  const int t  = threadIdx.y * 16 + threadIdx.x;
  const int tx = threadIdx.x, ty = threadIdx.y;
  float acc[3][4][4] = {};
  for (int kt = 0; kt < 8; ++kt){
    __syncthreads();   // previous iteration readers of As done
    #pragma unroll
    for (int i = 0; i < 8; ++i){
      int idx = t + i * 256;          // 0..2047
      int r = idx >> 5, k = idx & 31;
      As[r][k] = (n0 + r < NN) ? b2f(agg[(size_t)(n0 + r) * 256 + kt * 32 + k]) : 0.f;
    }
    for (int g = 0; g < 3; ++g){
      __syncthreads(); // previous Ws readers done + As writes visible
      #pragma unroll
      for (int i = 0; i < 8; ++i){
        int idx = t + i * 256;
        int k = idx >> 6, c = idx & 63;
        Ws[k][c] = postW[(size_t)(l * 832 + g * 256 + kt * 32 + k) * 64 + c];
      }
      __syncthreads();
      for (int k = 0; k < 32; ++k){
        float a[4];
        #pragma unroll
        for (int i = 0; i < 4; ++i) a[i] = As[ty * 4 + i][k];
        float4 bv = *(const float4*)&Ws[k][tx * 4];
        float b[4] = {bv.x, bv.y, bv.z, bv.w};
        #pragma unroll
        for (int i = 0; i < 4; ++i)
          #pragma unroll
          for (int j = 0; j < 4; ++j)
            acc[g][i][j] += a[i] * b[j];
      }
    }
  }
  #pragma unroll
  for (int i = 0; i < 4; ++i){
    int n = n0 + ty * 4 + i;
    if (n >= NN) continue;
    float am = amp[n], at = att[n];
    #pragma unroll
    for (int j = 0; j < 4; ++j){
      int c = tx * 4 + j;
      out[(size_t)n * 64 + c] += acc[0][i][j] + am * acc[1][i][j] + at * acc[2][i][j];
    }
  }
}

extern "C" void kernel_launch(void* const* d_in, const int* in_sizes, int n_in,
                              void* d_out, int out_size, void* d_ws, size_t ws_size,
                              hipStream_t stream){
  const int*   x     = (const int*)d_in[0];
  const int*   ei    = (const int*)d_in[1];
  const int*   ea    = (const int*)d_in[2];
  const float* aemb  = (const float*)d_in[3];
  const float* bemb  = (const float*)d_in[4];
  const float* preW  = (const float*)d_in[5];
  const float* preb  = (const float*)d_in[6];
  const float* postW = (const float*)d_in[7];
  const float* postb = (const float*)d_in[8];
  float* out = (float*)d_out;

  char* p = (char*)d_ws;
  auto alloc = [&](size_t bytes) -> char* {
    char* r = p;
    p += (bytes + 255) & ~(size_t)255;
    return r;
  };
  float* h0     = (float*)alloc((size_t)NN * 64 * 4);
  bf16*  AB     = (bf16*) alloc((size_t)NN * 640 * 2);
  bf16*  aggb   = (bf16*) alloc((size_t)NN * 256 * 2);
  int*   deg    = (int*)  alloc((size_t)NN * 4);
  int*   rowptr = (int*)  alloc((size_t)(NN + 1) * 4);
  int*   cursor = (int*)  alloc((size_t)NN * 4);
  float* amp    = (float*)alloc((size_t)NN * 4);
  float* att    = (float*)alloc((size_t)NN * 4);
  int*   code   = (int*)  alloc((size_t)NE * 4);
  int*   ssrc   = (int*)  alloc((size_t)NE * 4);
  int*   scode  = (int*)  alloc((size_t)NE * 4);
  bf16*  ctab   = (bf16*) alloc((size_t)512 * 5 * 64 * 2);
  float* whs    = (float*)alloc((size_t)64 * 64 * 4);
  float* bs     = (float*)alloc((size_t)64 * 4);
  int*   part   = (int*)  alloc((size_t)256 * 4);
  if ((size_t)(p - (char*)d_ws) > ws_size) return;  // workspace too small

  hipMemsetAsync(deg, 0, (size_t)NN * 4, stream);
  hipMemsetAsync(cursor, 0, (size_t)NN * 4, stream);

  k_h0<<<dim3((NN * 64 + 255) / 256), 256, 0, stream>>>(x, aemb, h0);
  k_deg_code<<<dim3((NE + 255) / 256), 256, 0, stream>>>(ei, ea, deg, code);
  int nblk = (NN + 255) / 256;   // 196
  k_scan1<<<dim3(nblk), 256, 0, stream>>>(deg, rowptr, part);
  k_scan2<<<dim3(1), 256, 0, stream>>>(part, nblk);
  k_scan3<<<dim3(nblk), 256, 0, stream>>>(rowptr, part, deg, amp, att);
  k_scatter<<<dim3((NE + 255) / 256), 256, 0, stream>>>(ei, code, rowptr, cursor, ssrc, scode);
  k_ctab<<<dim3(512, 5), 64, 0, stream>>>(bemb, preW, ctab);
  k_whsum<<<dim3(16), 256, 0, stream>>>(postW, postb, whs, bs);
  k_ab<<<dim3((NN + 63) / 64, 10), dim3(16, 16), 0, stream>>>(h0, preW, preb, AB);
  k_hlin<<<dim3((NN + 63) / 64), dim3(16, 16), 0, stream>>>(h0, whs, bs, out);
  for (int l = 0; l < 5; ++l){
    k_agg<<<dim3((NN + 3) / 4), 256, 0, stream>>>(AB, ctab, rowptr, ssrc, scode, l, aggb);
    k_post<<<dim3((NN + 63) / 64), dim3(16, 16), 0, stream>>>(aggb, postW, l, amp, att, out);
  }
}

// Round 2
// 522.787 us; speedup vs baseline: 1.9386x; 1.9386x over previous
//
#include <hip/hip_runtime.h>
#include <hip/hip_bf16.h>

#define NN 50000
#define NE 400000
#define AVG_LOG_F 2.1972245773362196f
#define EPSV 1e-5f

typedef __hip_bfloat16 bf16;
typedef __attribute__((ext_vector_type(8))) short short8v;
typedef __attribute__((ext_vector_type(4))) float f32x4;

__device__ __forceinline__ float b2f(bf16 v){ return __bfloat162float(v); }
__device__ __forceinline__ bf16  f2b(float v){ return __float2bfloat16(v); }

// ---------- h0[n][d] = sum_c atom_emb[c][x[n][c]][d] ----------
__global__ void k_h0(const int* __restrict__ x, const float* __restrict__ aemb,
                     float* __restrict__ h0){
  int idx = blockIdx.x * 256 + threadIdx.x;
  if (idx >= NN * 64) return;
  int n = idx >> 6, d = idx & 63;
  float acc = 0.f;
  #pragma unroll
  for (int c = 0; c < 9; ++c){
    int a = x[n * 9 + c];
    acc += aemb[(c * 64 + a) * 64 + d];
  }
  h0[idx] = acc;
}

// ---------- degree histogram + bond code ----------
__global__ void k_deg_code(const int* __restrict__ ei, const int* __restrict__ ea,
                           int* __restrict__ deg, int* __restrict__ code){
  int e = blockIdx.x * 256 + threadIdx.x;
  if (e >= NE) return;
  int dst = ei[NE + e];
  atomicAdd(&deg[dst], 1);
  code[e] = ea[e * 3] + 8 * ea[e * 3 + 1] + 64 * ea[e * 3 + 2];
}

// ---------- exclusive scan of deg -> rowptr (3 kernels) ----------
__global__ void k_scan1(const int* __restrict__ deg, int* __restrict__ rowptr,
                        int* __restrict__ part){
  __shared__ int s[256];
  int t = threadIdx.x, i = blockIdx.x * 256 + t;
  int v = (i < NN) ? deg[i] : 0;
  s[t] = v; __syncthreads();
  for (int off = 1; off < 256; off <<= 1){
    int xv = (t >= off) ? s[t - off] : 0;
    __syncthreads();
    s[t] += xv;
    __syncthreads();
  }
  if (i < NN) rowptr[i] = s[t] - v;
  if (t == 255) part[blockIdx.x] = s[255];
}

__global__ void k_scan2(int* __restrict__ part, int nblk){
  __shared__ int s[256];
  int t = threadIdx.x;
  int v = (t < nblk) ? part[t] : 0;
  s[t] = v; __syncthreads();
  for (int off = 1; off < 256; off <<= 1){
    int xv = (t >= off) ? s[t - off] : 0;
    __syncthreads();
    s[t] += xv;
    __syncthreads();
  }
  if (t < nblk) part[t] = s[t] - v;   // exclusive block offsets
}

__global__ void k_scan3(int* __restrict__ rowptr, const int* __restrict__ part,
                        const int* __restrict__ deg, float* __restrict__ amp,
                        float* __restrict__ att){
  int i = blockIdx.x * 256 + threadIdx.x;
  if (i < NN){
    rowptr[i] += part[blockIdx.x];
    int d = deg[i];
    float ld = logf((float)max(d, 1) + 1.0f);
    amp[i] = ld / AVG_LOG_F;
    att[i] = AVG_LOG_F / ld;
  }
  if (i == 0) rowptr[NN] = NE;
}

// ---------- scatter edges into CSR order ----------
__global__ void k_scatter(const int* __restrict__ ei, const int* __restrict__ code,
                          const int* __restrict__ rowptr, int* __restrict__ cursor,
                          int* __restrict__ ssrc, int* __restrict__ scode){
  int e = blockIdx.x * 256 + threadIdx.x;
  if (e >= NE) return;
  int dst = ei[NE + e];
  int pos = rowptr[dst] + atomicAdd(&cursor[dst], 1);
  ssrc[pos]  = ei[e];
  scode[pos] = code[e];
}

// ---------- C table: ctab[code][l][d] = (sum_c bond_emb[c][attr_c]) @ preW_e[l] ----------
__global__ void k_ctab(const float* __restrict__ bemb, const float* __restrict__ preW,
                       bf16* __restrict__ ctab){
  __shared__ float et[64];
  int cb = blockIdx.x, l = blockIdx.y, t = threadIdx.x;
  int a0 = cb & 7, a1 = (cb >> 3) & 7, a2 = (cb >> 6) & 7;
  et[t] = bemb[(0 * 8 + a0) * 64 + t] + bemb[(1 * 8 + a1) * 64 + t] + bemb[(2 * 8 + a2) * 64 + t];
  __syncthreads();
  float acc = 0.f;
  const float* W = preW + (l * 192 + 128) * 64;
  for (int k = 0; k < 64; ++k) acc += et[k] * W[k * 64 + t];
  ctab[(cb * 5 + l) * 64 + t] = f2b(acc);
}

// ---------- Whsum = sum_l post_W[l][768:832], bsum = sum_l post_b[l] ----------
__global__ void k_whsum(const float* __restrict__ postW, const float* __restrict__ postb,
                        float* __restrict__ whs, float* __restrict__ bs){
  int idx = blockIdx.x * 256 + threadIdx.x;
  if (idx < 4096){
    int k = idx >> 6, d = idx & 63;
    float a = 0.f;
    for (int l = 0; l < 5; ++l) a += postW[(size_t)(l * 832 + 768 + k) * 64 + d];
    whs[idx] = a;
  }
  if (idx < 64){
    float a = 0.f;
    for (int l = 0; l < 5; ++l) a += postb[l * 64 + idx];
    bs[idx] = a;
  }
}

// ---------- Wt[l][cc][k] = postW[l][g*256 + k][c], cc=g*64+c  (fragment-ready, bf16) ----------
__global__ void k_wt(const float* __restrict__ postW, bf16* __restrict__ Wt){
  int idx = blockIdx.x * 256 + threadIdx.x;
  if (idx >= 5 * 192 * 256) return;
  int l = idx / (192 * 256);
  int rem = idx % (192 * 256);
  int cc = rem >> 8;      // 0..191
  int k  = rem & 255;     // 0..255
  int g = cc >> 6, c = cc & 63;
  Wt[idx] = f2b(postW[((size_t)l * 832 + g * 256 + k) * 64 + c]);
}

// ---------- AB GEMM: AB[n][s][64], s<5: A_l=h0@Wdst+b ; s>=5: B_l=h0@Wsrc ----------
__global__ __launch_bounds__(256) void k_ab(const float* __restrict__ h0,
                                            const float* __restrict__ preW,
                                            const float* __restrict__ preb,
                                            bf16* __restrict__ AB){
  __shared__ float As[64][65];  // [row][k]
  __shared__ float Ws[64][64];  // [k][col]
  const int s  = blockIdx.y;
  const int n0 = blockIdx.x * 64;
  const int t  = threadIdx.y * 16 + threadIdx.x;
  const int l  = (s < 5) ? s : (s - 5);
  const int rbase = l * 192 + ((s < 5) ? 0 : 64);
  #pragma unroll
  for (int i = 0; i < 16; ++i){
    int idx = t + i * 256;
    int r = idx >> 6, k = idx & 63;
    As[r][k] = (n0 + r < NN) ? h0[(size_t)(n0 + r) * 64 + k] : 0.f;
    Ws[r][k] = preW[(size_t)(rbase + r) * 64 + k];
  }
  __syncthreads();
  const int tx = threadIdx.x, ty = threadIdx.y;
  float acc[4][4] = {};
  for (int k = 0; k < 64; ++k){
    float a[4];
    #pragma unroll
    for (int i = 0; i < 4; ++i) a[i] = As[ty * 4 + i][k];
    float4 bv = *(const float4*)&Ws[k][tx * 4];
    float b[4] = {bv.x, bv.y, bv.z, bv.w};
    #pragma unroll
    for (int i = 0; i < 4; ++i)
      #pragma unroll
      for (int j = 0; j < 4; ++j)
        acc[i][j] += a[i] * b[j];
  }
  #pragma unroll
  for (int i = 0; i < 4; ++i){
    int n = n0 + ty * 4 + i;
    if (n >= NN) continue;
    #pragma unroll
    for (int j = 0; j < 4; ++j){
      int c = tx * 4 + j;
      float v = acc[i][j] + ((s < 5) ? preb[l * 64 + c] : 0.f);
      AB[(size_t)n * 640 + s * 64 + c] = f2b(v);
    }
  }
}

// ---------- h_lin = h0 + h0@Whsum + bsum  (written to d_out as base) ----------
__global__ __launch_bounds__(256) void k_hlin(const float* __restrict__ h0,
                                              const float* __restrict__ whs,
                                              const float* __restrict__ bs,
                                              float* __restrict__ out){
  __shared__ float As[64][65];
  __shared__ float Ws[64][64];
  const int n0 = blockIdx.x * 64;
  const int t  = threadIdx.y * 16 + threadIdx.x;
  #pragma unroll
  for (int i = 0; i < 16; ++i){
    int idx = t + i * 256;
    int r = idx >> 6, k = idx & 63;
    As[r][k] = (n0 + r < NN) ? h0[(size_t)(n0 + r) * 64 + k] : 0.f;
    Ws[r][k] = whs[idx];
  }
  __syncthreads();
  const int tx = threadIdx.x, ty = threadIdx.y;
  float acc[4][4] = {};
  for (int k = 0; k < 64; ++k){
    float a[4];
    #pragma unroll
    for (int i = 0; i < 4; ++i) a[i] = As[ty * 4 + i][k];
    float4 bv = *(const float4*)&Ws[k][tx * 4];
    float b[4] = {bv.x, bv.y, bv.z, bv.w};
    #pragma unroll
    for (int i = 0; i < 4; ++i)
      #pragma unroll
      for (int j = 0; j < 4; ++j)
        acc[i][j] += a[i] * b[j];
  }
  #pragma unroll
  for (int i = 0; i < 4; ++i){
    int n = n0 + ty * 4 + i;
    if (n >= NN) continue;
    #pragma unroll
    for (int j = 0; j < 4; ++j){
      int c = tx * 4 + j;
      out[(size_t)n * 64 + c] = acc[i][j] + h0[(size_t)n * 64 + c] + bs[c];
    }
  }
}

// ---------- per-node aggregation for layer l -> agg[n][256] bf16 ----------
__global__ __launch_bounds__(256) void k_agg(const bf16* __restrict__ AB,
                                             const bf16* __restrict__ ctab,
                                             const int* __restrict__ rowptr,
                                             const int* __restrict__ ssrc,
                                             const int* __restrict__ scode,
                                             const int l, bf16* __restrict__ agg){
  int w = threadIdx.x >> 6, lane = threadIdx.x & 63;
  int n = blockIdx.x * 4 + w;
  if (n >= NN) return;
  int r0 = rowptr[n], r1 = rowptr[n + 1];
  float s = 0.f, sq = 0.f, mx = -1e30f, mn = 1e30f;
  for (int j = r0; j < r1; ++j){
    int src = ssrc[j], cd = scode[j];
    float tv = b2f(AB[(size_t)src * 640 + (5 + l) * 64 + lane]) +
               b2f(ctab[(cd * 5 + l) * 64 + lane]);
    s += tv; sq += tv * tv;
    mx = fmaxf(mx, tv); mn = fminf(mn, tv);
  }
  int d = r1 - r0;
  float degc = (float)((d > 0) ? d : 1);
  float K = b2f(AB[(size_t)n * 640 + l * 64 + lane]);   // includes pre_b
  float mean = ((float)d * K + s) / degc;
  float MX = (d > 0) ? (K + mx) : 0.f;
  float MN = (d > 0) ? (K + mn) : 0.f;
  float mu = s / degc;
  float var = fmaxf(sq / degc - mu * mu, 0.f);
  float sd = sqrtf(var + EPSV);
  size_t base = (size_t)n * 256 + lane;
  agg[base]       = f2b(mean);
  agg[base + 64]  = f2b(MX);
  agg[base + 128] = f2b(MN);
  agg[base + 192] = f2b(sd);
}

// ---------- posttrans layer l via MFMA: out += U + amp*V + att*W ----------
// agg[N,256] @ Wt_l[256,192] ; tile 128 rows x 192 cols, 4 waves x (32 rows x 192 cols)
__global__ __launch_bounds__(256) void k_post_mfma(const bf16* __restrict__ agg,
                                                   const bf16* __restrict__ Wt,
                                                   const int l,
                                                   const float* __restrict__ amp,
                                                   const float* __restrict__ att,
                                                   float* __restrict__ out){
  __shared__ short As[128][40];   // rows x k-tile(32), pad to 40 (80B stride)
  __shared__ short Bs[192][40];   // cols x k-tile(32), fragment-ready (transposed W)
  const int t = threadIdx.x;
  const int n0 = blockIdx.x * 128;
  const int lane = t & 63, wid = t >> 6;
  const int rw = wid * 32;
  const short* Wl = (const short*)(Wt + (size_t)l * 192 * 256);
  const short* ag = (const short*)agg;

  f32x4 acc[2][12] = {};

  for (int kt = 0; kt < 8; ++kt){
    // stage A: 128 rows x 32 k, 2 x short8 per thread
    {
      int r = t >> 1, h = t & 1;
      int n = n0 + r;
      short8v v0 = {0,0,0,0,0,0,0,0}, v1 = {0,0,0,0,0,0,0,0};
      if (n < NN){
        const short* src = ag + (size_t)n * 256 + kt * 32 + h * 16;
        v0 = *(const short8v*)src;
        v1 = *(const short8v*)(src + 8);
      }
      *(short8v*)&As[r][h * 16]     = v0;
      *(short8v*)&As[r][h * 16 + 8] = v1;
    }
    // stage B: 192 cols x 32 k
    #pragma unroll
    for (int i = 0; i < 3; ++i){
      int idx = t + i * 256;          // 0..767
      int cc = idx >> 2, h = idx & 3;
      *(short8v*)&Bs[cc][h * 8] =
          *(const short8v*)(Wl + (size_t)cc * 256 + kt * 32 + h * 8);
    }
    __syncthreads();
    short8v af0 = *(const short8v*)&As[rw + (lane & 15)][(lane >> 4) * 8];
    short8v af1 = *(const short8v*)&As[rw + 16 + (lane & 15)][(lane >> 4) * 8];
    #pragma unroll
    for (int j = 0; j < 12; ++j){
      short8v bfj = *(const short8v*)&Bs[j * 16 + (lane & 15)][(lane >> 4) * 8];
      acc[0][j] = __builtin_amdgcn_mfma_f32_16x16x32_bf16(af0, bfj, acc[0][j], 0, 0, 0);
      acc[1][j] = __builtin_amdgcn_mfma_f32_16x16x32_bf16(af1, bfj, acc[1][j], 0, 0, 0);
    }
    __syncthreads();
  }

  // epilogue: C/D layout col=lane&15, row=(lane>>4)*4+reg
  #pragma unroll
  for (int i = 0; i < 2; ++i){
    #pragma unroll
    for (int r = 0; r < 4; ++r){
      int n = n0 + rw + i * 16 + (lane >> 4) * 4 + r;
      if (n >= NN) continue;
      float am = amp[n], at = att[n];
      #pragma unroll
      for (int j4 = 0; j4 < 4; ++j4){
        int c = j4 * 16 + (lane & 15);
        float v = acc[i][j4][r] + am * acc[i][4 + j4][r] + at * acc[i][8 + j4][r];
        out[(size_t)n * 64 + c] += v;
      }
    }
  }
}

extern "C" void kernel_launch(void* const* d_in, const int* in_sizes, int n_in,
                              void* d_out, int out_size, void* d_ws, size_t ws_size,
                              hipStream_t stream){
  const int*   x     = (const int*)d_in[0];
  const int*   ei    = (const int*)d_in[1];
  const int*   ea    = (const int*)d_in[2];
  const float* aemb  = (const float*)d_in[3];
  const float* bemb  = (const float*)d_in[4];
  const float* preW  = (const float*)d_in[5];
  const float* preb  = (const float*)d_in[6];
  const float* postW = (const float*)d_in[7];
  const float* postb = (const float*)d_in[8];
  float* out = (float*)d_out;

  char* p = (char*)d_ws;
  auto alloc = [&](size_t bytes) -> char* {
    char* r = p;
    p += (bytes + 255) & ~(size_t)255;
    return r;
  };
  float* h0     = (float*)alloc((size_t)NN * 64 * 4);
  bf16*  AB     = (bf16*) alloc((size_t)NN * 640 * 2);
  bf16*  aggb   = (bf16*) alloc((size_t)NN * 256 * 2);
  int*   deg    = (int*)  alloc((size_t)NN * 4);
  int*   rowptr = (int*)  alloc((size_t)(NN + 1) * 4);
  int*   cursor = (int*)  alloc((size_t)NN * 4);
  float* amp    = (float*)alloc((size_t)NN * 4);
  float* att    = (float*)alloc((size_t)NN * 4);
  int*   code   = (int*)  alloc((size_t)NE * 4);
  int*   ssrc   = (int*)  alloc((size_t)NE * 4);
  int*   scode  = (int*)  alloc((size_t)NE * 4);
  bf16*  ctab   = (bf16*) alloc((size_t)512 * 5 * 64 * 2);
  float* whs    = (float*)alloc((size_t)64 * 64 * 4);
  float* bs     = (float*)alloc((size_t)64 * 4);
  int*   part   = (int*)  alloc((size_t)256 * 4);
  bf16*  Wt     = (bf16*) alloc((size_t)5 * 192 * 256 * 2);
  if ((size_t)(p - (char*)d_ws) > ws_size) return;  // workspace too small

  hipMemsetAsync(deg, 0, (size_t)NN * 4, stream);
  hipMemsetAsync(cursor, 0, (size_t)NN * 4, stream);

  k_h0<<<dim3((NN * 64 + 255) / 256), 256, 0, stream>>>(x, aemb, h0);
  k_deg_code<<<dim3((NE + 255) / 256), 256, 0, stream>>>(ei, ea, deg, code);
  int nblk = (NN + 255) / 256;   // 196
  k_scan1<<<dim3(nblk), 256, 0, stream>>>(deg, rowptr, part);
  k_scan2<<<dim3(1), 256, 0, stream>>>(part, nblk);
  k_scan3<<<dim3(nblk), 256, 0, stream>>>(rowptr, part, deg, amp, att);
  k_scatter<<<dim3((NE + 255) / 256), 256, 0, stream>>>(ei, code, rowptr, cursor, ssrc, scode);
  k_ctab<<<dim3(512, 5), 64, 0, stream>>>(bemb, preW, ctab);
  k_whsum<<<dim3(16), 256, 0, stream>>>(postW, postb, whs, bs);
  k_wt<<<dim3((5 * 192 * 256 + 255) / 256), 256, 0, stream>>>(postW, Wt);
  k_ab<<<dim3((NN + 63) / 64, 10), dim3(16, 16), 0, stream>>>(h0, preW, preb, AB);
  k_hlin<<<dim3((NN + 63) / 64), dim3(16, 16), 0, stream>>>(h0, whs, bs, out);
  for (int l = 0; l < 5; ++l){
    k_agg<<<dim3((NN + 3) / 4), 256, 0, stream>>>(AB, ctab, rowptr, ssrc, scode, l, aggb);
    k_post_mfma<<<dim3((NN + 127) / 128), 256, 0, stream>>>(aggb, Wt, l, amp, att, out);
  }
}